// Round 8
// baseline (229.634 us; speedup 1.0000x reference)
//
#include <hip/hip_runtime.h>
#include <hip/hip_bf16.h>

// Problem constants (GPT-2 style attention block)
#define BB 8
#define SS 1024
#define NXX 1024
#define HH 16
#define DD 64
#define MM (BB * SS)

typedef __attribute__((ext_vector_type(8))) short short8;   // 8 bf16 = 4 VGPRs
typedef __attribute__((ext_vector_type(4))) short short4v;  // 4 bf16 = 8 B
typedef __attribute__((ext_vector_type(4))) float float4v;  // MFMA C/D

static __device__ inline short bf16bits(float v) {
    __hip_bfloat16 t = __float2bfloat16(v);
    return *reinterpret_cast<short*>(&t);
}

// ---------------------------------------------------------------------------
// Prep kernel: one launch does x->bf16 convert + both weight transposes.
// ---------------------------------------------------------------------------
__global__ __launch_bounds__(256) void prep_kernel(
    const float* __restrict__ x, __hip_bfloat16* __restrict__ xb,
    const float* __restrict__ w_attn, __hip_bfloat16* __restrict__ wT_attn,
    const float* __restrict__ w_proj, __hip_bfloat16* __restrict__ wT_proj)
{
    __shared__ __hip_bfloat16 tile[32][33];
    const int blk = blockIdx.x;
    const int tid = threadIdx.x;

    if (blk < 8192) {
        int i = blk * 1024 + tid * 4;
        float4 v = *(const float4*)(x + i);
        xb[i + 0] = __float2bfloat16(v.x);
        xb[i + 1] = __float2bfloat16(v.y);
        xb[i + 2] = __float2bfloat16(v.z);
        xb[i + 3] = __float2bfloat16(v.w);
        return;
    }
    const float* W;
    __hip_bfloat16* Wt;
    int K, N, idx;
    if (blk < 8192 + 3072) { idx = blk - 8192;  W = w_attn; Wt = wT_attn; K = NXX; N = 3 * NXX; }
    else                   { idx = blk - 11264; W = w_proj; Wt = wT_proj; K = NXX; N = NXX; }
    const int k0 = (idx % (K / 32)) * 32;
    const int n0 = (idx / (K / 32)) * 32;
    const int tx = tid % 32;
    const int ty = tid / 32;
#pragma unroll
    for (int p = 0; p < 4; ++p) {
        int k = ty + p * 8;
        tile[k][tx] = __float2bfloat16(W[(size_t)(k0 + k) * N + n0 + tx]);
    }
    __syncthreads();
#pragma unroll
    for (int p = 0; p < 4; ++p) {
        int nn = ty + p * 8;
        Wt[(size_t)(n0 + nn) * K + k0 + tx] = tile[tx][nn];
    }
}

#define WAIT_LGKM0_FENCED()                                                    \
    asm volatile("s_waitcnt lgkmcnt(0)" ::: "memory");                         \
    __builtin_amdgcn_sched_barrier(0);

// ---------------------------------------------------------------------------
// gemm256: BMxBN 8-wave pipelined GEMM, <=64 KiB static LDS (round-4
// HW-verified at <1,256,128>: 66.7us QKV, MfmaUtil 32%, 0 bank conflicts).
// Used for proj (and as QKV fallback if dynamic-LDS opt-in is unavailable).
// ---------------------------------------------------------------------------
#define STAGE_A(DST, kk)                                                       \
    {                                                                          \
        _Pragma("unroll") for (int j_ = 0; j_ < LA; ++j_) {                    \
            const __hip_bfloat16* s_ = aSrc + (size_t)(j_ * 128) * K + (kk);   \
            char* d_ = (char*)(DST) + j_ * 8192 + (wave << 10);                \
            __builtin_amdgcn_global_load_lds(                                  \
                (const __attribute__((address_space(1))) void*)s_,             \
                (__attribute__((address_space(3))) void*)d_, 16, 0, 0);        \
        }                                                                      \
    }

#define STAGE_B(DST, kk)                                                       \
    {                                                                          \
        _Pragma("unroll") for (int j_ = 0; j_ < LB; ++j_) {                    \
            const __hip_bfloat16* s_ = bSrc + (size_t)(j_ * 128) * K + (kk);   \
            char* d_ = (char*)(DST) + j_ * 8192 + (wave << 10);                \
            __builtin_amdgcn_global_load_lds(                                  \
                (const __attribute__((address_space(1))) void*)s_,             \
                (__attribute__((address_space(3))) void*)d_, 16, 0, 0);        \
        }                                                                      \
    }

#define WAIT_VMCNT_LT()                                                        \
    if constexpr (LT == 3) { asm volatile("s_waitcnt vmcnt(3)" ::: "memory"); }\
    else                   { asm volatile("s_waitcnt vmcnt(2)" ::: "memory"); }

template <int MODE, int BM, int BN>
__global__ __launch_bounds__(512, 2) void gemm256(
    const __hip_bfloat16* __restrict__ A,   // M x K row-major
    const __hip_bfloat16* __restrict__ Bt,  // N x K row-major
    const float* __restrict__ bias,
    void* __restrict__ Cv,                  // M x N
    __hip_bfloat16* __restrict__ vT,        // MODE 1 only
    int M, int K, int N)
{
    constexpr int NWM = BM / 64;
    constexpr int NWN = 8 / NWM;
    constexpr int WCOLS = BN / NWN;
    constexpr int NF = WCOLS / 16;
    constexpr int ASZ = BM * 64;
    constexpr int BSZ = BN * 64;
    constexpr int LA = BM / 128;
    constexpr int LB = BN / 128;
    constexpr int LT = LA + LB;

    __shared__ __attribute__((aligned(16))) char smem[3 * ASZ + 2 * BSZ];

    const int tid  = threadIdx.x;
    const int wave = tid >> 6;
    const int lane = tid & 63;
    const int wm = (wave / NWN) * 64;
    const int wn = (wave % NWN) * WCOLS;

    const int nwg = (int)gridDim.x;
    const int cpx = nwg >> 3;
    const int bid = (int)blockIdx.x;
    const int swz = (bid & 7) * cpx + (bid >> 3);
    const int ntN = N / BN;
    const int width = ntN << 3;
    const int group = swz / width;
    const int w = swz % width;
    const int m0 = (group * 8 + (w & 7)) * BM;
    const int n0 = (w >> 3) * BN;

    const int NT = K >> 5;

    const int row_s  = tid >> 2;
    const int srccol = (((tid & 3) ^ ((tid >> 3) & 3)) << 3);
    const __hip_bfloat16* aSrc = A  + (size_t)(m0 + row_s) * K + srccol;
    const __hip_bfloat16* bSrc = Bt + (size_t)(n0 + row_s) * K + srccol;

    const int l15 = lane & 15, q4 = lane >> 4;
    const int sslot = (q4 ^ ((l15 >> 1) & 3)) << 4;
    const int offA = (wm + l15) * 64 + sslot;
    const int offB = (wn + l15) * 64 + sslot;

    float4v acc[4][NF];
#pragma unroll
    for (int i = 0; i < 4; ++i)
#pragma unroll
        for (int j = 0; j < NF; ++j) acc[i][j] = (float4v){0.f, 0.f, 0.f, 0.f};

    char* const Abuf0 = (char*)smem;
    char* const Bbuf0 = (char*)smem + 3 * ASZ;

    STAGE_A(Abuf0,       0);
    STAGE_B(Bbuf0,       0);
    STAGE_A(Abuf0 + ASZ, 32);
    STAGE_B(Bbuf0 + BSZ, 32);
    WAIT_VMCNT_LT();
    __builtin_amdgcn_s_barrier();

    int ia = 0;
    for (int t = 0; t < NT; ++t) {
        const char* Ab = Abuf0 + ia * ASZ;
        char* Bb = Bbuf0 + (t & 1) * BSZ;
        const int ia2 = (ia == 0) ? 2 : ia - 1;

        short8 a[4], b[NF];

#pragma unroll
        for (int mf = 0; mf < 2; ++mf) a[mf] = *(const short8*)(Ab + offA + mf * 1024);
#pragma unroll
        for (int nf = 0; nf < NF; ++nf) b[nf] = *(const short8*)(Bb + offB + nf * 1024);
        if (t + 2 < NT) STAGE_A(Abuf0 + ia2 * ASZ, (t + 2) << 5);
        __builtin_amdgcn_s_barrier();
        WAIT_LGKM0_FENCED();
        __builtin_amdgcn_s_setprio(1);
#pragma unroll
        for (int mf = 0; mf < 2; ++mf)
#pragma unroll
            for (int nf = 0; nf < NF; ++nf)
                acc[mf][nf] = __builtin_amdgcn_mfma_f32_16x16x32_bf16(
                    a[mf], b[nf], acc[mf][nf], 0, 0, 0);
        __builtin_amdgcn_s_setprio(0);
        __builtin_amdgcn_s_barrier();

#pragma unroll
        for (int mf = 2; mf < 4; ++mf) a[mf] = *(const short8*)(Ab + offA + mf * 1024);
        if (t + 2 < NT) {
            STAGE_B(Bb, (t + 2) << 5);
            WAIT_VMCNT_LT();
        } else if (t + 1 < NT) {
            asm volatile("s_waitcnt vmcnt(0)" ::: "memory");
        }
        __builtin_amdgcn_s_barrier();
        WAIT_LGKM0_FENCED();
        __builtin_amdgcn_s_setprio(1);
#pragma unroll
        for (int mf = 2; mf < 4; ++mf)
#pragma unroll
            for (int nf = 0; nf < NF; ++nf)
                acc[mf][nf] = __builtin_amdgcn_mfma_f32_16x16x32_bf16(
                    a[mf], b[nf], acc[mf][nf], 0, 0, 0);
        __builtin_amdgcn_s_setprio(0);
        __builtin_amdgcn_s_barrier();

        ia = (ia == 2) ? 0 : ia + 1;
    }

    const int cr = q4 * 4;
    const int cc = l15;

    if (MODE == 1 && n0 >= 2048) {
        const int bb = m0 / SS;
#pragma unroll
        for (int mf = 0; mf < 4; ++mf) {
            int grow = m0 + wm + mf * 16 + cr;
            int ssr = grow & (SS - 1);
#pragma unroll
            for (int nf = 0; nf < NF; ++nf) {
                int gcol = n0 + wn + nf * 16 + cc;
                float bv = bias[gcol];
                int col = gcol - 2048;
                int hh = col >> 6, dd = col & 63;
                short4v pk;
#pragma unroll
                for (int r = 0; r < 4; ++r) pk[r] = bf16bits(acc[mf][nf][r] + bv);
                *(short4v*)(vT + (size_t)((bb * HH + hh) * 64 + dd) * SS + ssr) = pk;
            }
        }
    } else {
        const float qs = (MODE == 1 && n0 < 1024) ? 0.125f : 1.0f;
#pragma unroll
        for (int mf = 0; mf < 4; ++mf) {
            int grow = m0 + wm + mf * 16 + cr;
#pragma unroll
            for (int nf = 0; nf < NF; ++nf) {
                int gcol = n0 + wn + nf * 16 + cc;
                float bv = bias[gcol];
#pragma unroll
                for (int r = 0; r < 4; ++r) {
                    float v = (acc[mf][nf][r] + bv) * qs;
                    if constexpr (MODE == 1)
                        ((__hip_bfloat16*)Cv)[(size_t)(grow + r) * N + gcol] =
                            __float2bfloat16(v);
                    else
                        ((float*)Cv)[(size_t)(grow + r) * N + gcol] = v;
                }
            }
        }
    }
}

// ---------------------------------------------------------------------------
// gemm8k: 256x256, BK=64, 8-wave, 4-phase, 128 KiB DYNAMIC LDS (opt-in).
// Round-1 schedule (paper-verified; never ran only due to static-LDS limit):
//   2 buffers x (A 32K + B 32K). Per K-tile t (buf=t&1), 4 phases, each
//   {ds-subtile | 1 half-tile prefetch | bar; lgkm0+fence; prio1; 16 MFMA;
//    prio0; bar}:
//   ph0: A[m0-3]k0 + Bk0 (8xb128) | stage A(t+1)h0 -> other buf
//   ph1: A[m0-3]k1 + Bk1 (8)      | stage A(t+1)h1
//   ph2: A[m4-7]k0 (4)            | stage B(t+2)h0 -> CUR buf's B (B(t)
//                                   fully reg-resident after ph1's bar)
//   ph3: A[m4-7]k1 (4)            | stage B(t+2)h1 | vmcnt(4)
// Ledger at ph3: A(t+1)[4] + B(t+2)[4] issued this tile on top of B(t+1)[4]
// = 12 -> vmcnt(4) retires A(t+1)+B(t+1), keeps B(t+2) in flight (issued a
// full K-tile early). Tail t=NT-2: vmcnt(0). 64 MFMA/wave/K-tile, 16 per
// barrier-pair (2x gemm256's density). Grouped-M (GM=8) + XCD swizzle.
// Swizzle: 16B slots of 128B rows, slot ^= row&7 (inverse on global src).
// ---------------------------------------------------------------------------
#define STAGE8(SRCBASE, DST, half, kk)                                         \
    {                                                                          \
        _Pragma("unroll") for (int j_ = 0; j_ < 2; ++j_) {                     \
            const __hip_bfloat16* s_ =                                         \
                (SRCBASE) + (size_t)((half) * 128 + j_ * 64) * K + (kk);       \
            char* d_ = (char*)(DST) + (half) * 16384 + j_ * 8192 + (wave << 10); \
            __builtin_amdgcn_global_load_lds(                                  \
                (const __attribute__((address_space(1))) void*)s_,             \
                (__attribute__((address_space(3))) void*)d_, 16, 0, 0);        \
        }                                                                      \
    }

template <int MODE>
__global__ __launch_bounds__(512, 2) void gemm8k(
    const __hip_bfloat16* __restrict__ A,   // M x K row-major
    const __hip_bfloat16* __restrict__ Bt,  // N x K row-major
    const float* __restrict__ bias,
    void* __restrict__ Cv,                  // M x N
    __hip_bfloat16* __restrict__ vT,        // MODE 1 only
    int M, int K, int N)
{
    extern __shared__ char smem[];

    const int tid  = threadIdx.x;
    const int wave = tid >> 6;
    const int lane = tid & 63;
    const int wr = wave >> 2;   // 0..1: M half (128 rows/wave)
    const int wc = wave & 3;    // 0..3: N quarter (64 cols/wave)

    // XCD swizzle + grouped-M (GM=8, N-fastest) for L2 locality.
    const int nwg = (int)gridDim.x;
    const int cpx = nwg >> 3;
    const int bid = (int)blockIdx.x;
    const int swz = (bid & 7) * cpx + (bid >> 3);
    const int ntN = N >> 8;
    const int width = ntN << 3;
    const int group = swz / width;
    const int w = swz % width;
    const int m0 = ((group << 3) + (w & 7)) << 8;
    const int n0 = (w >> 3) << 8;

    const int NT = K >> 6;   // BK=64

    // staging: 8 threads/row (128B), pre-swizzled source (rule #21).
    const int row_s  = tid >> 3;
    const int slot_s = tid & 7;
    const int srccol = ((slot_s ^ (row_s & 7)) << 3);   // bf16 elems
    const __hip_bfloat16* aSrc = A  + (size_t)(m0 + row_s) * K + srccol;
    const __hip_bfloat16* bSrc = Bt + (size_t)(n0 + row_s) * K + srccol;

    // fragment reads: byte = row*128 + ((kslot) ^ (row&7))*16
    const int l15 = lane & 15, q4 = lane >> 4, xr = lane & 7;
    const int sl0 = (q4 ^ xr) << 4;
    const int sl1 = ((4 + q4) ^ xr) << 4;
    const int offA0 = ((wr << 7) + l15) * 128 + sl0;
    const int offA1 = ((wr << 7) + l15) * 128 + sl1;
    const int offB0 = ((wc << 6) + l15) * 128 + sl0;
    const int offB1 = ((wc << 6) + l15) * 128 + sl1;

    float4v acc[8][4];
#pragma unroll
    for (int i = 0; i < 8; ++i)
#pragma unroll
        for (int j = 0; j < 4; ++j) acc[i][j] = (float4v){0.f, 0.f, 0.f, 0.f};

    // prologue: T0.{A,B} + T1.B; wait until T0 landed (T1.B stays in flight)
    STAGE8(aSrc, smem, 0, 0);
    STAGE8(aSrc, smem, 1, 0);
    STAGE8(bSrc, smem + 32768, 0, 0);
    STAGE8(bSrc, smem + 32768, 1, 0);
    if (NT > 1) {
        STAGE8(bSrc, smem + 65536 + 32768, 0, 64);
        STAGE8(bSrc, smem + 65536 + 32768, 1, 64);
        asm volatile("s_waitcnt vmcnt(4)" ::: "memory");
    } else {
        asm volatile("s_waitcnt vmcnt(0)" ::: "memory");
    }
    __builtin_amdgcn_s_barrier();

    for (int t = 0; t < NT; ++t) {
        const char* Ab = smem + ((t & 1) << 16);
        const char* Bb = Ab + 32768;
        char* AbN = (char*)smem + (((t + 1) & 1) << 16);
        char* BbC = (char*)Ab + 32768;

        short8 a0[4], a1[4], b0[4], b1[4];

        // ---- phase 0: A[m0-3]k0 + B k0; prefetch A(t+1)h0
#pragma unroll
        for (int mf = 0; mf < 4; ++mf) a0[mf] = *(const short8*)(Ab + offA0 + mf * 2048);
#pragma unroll
        for (int nf = 0; nf < 4; ++nf) b0[nf] = *(const short8*)(Bb + offB0 + nf * 2048);
        if (t + 1 < NT) STAGE8(aSrc, AbN, 0, (t + 1) << 6);
        __builtin_amdgcn_s_barrier();
        WAIT_LGKM0_FENCED();
        __builtin_amdgcn_s_setprio(1);
#pragma unroll
        for (int mf = 0; mf < 4; ++mf)
#pragma unroll
            for (int nf = 0; nf < 4; ++nf)
                acc[mf][nf] = __builtin_amdgcn_mfma_f32_16x16x32_bf16(
                    a0[mf], b0[nf], acc[mf][nf], 0, 0, 0);
        __builtin_amdgcn_s_setprio(0);
        __builtin_amdgcn_s_barrier();

        // ---- phase 1: A[m0-3]k1 + B k1; prefetch A(t+1)h1
#pragma unroll
        for (int mf = 0; mf < 4; ++mf) a1[mf] = *(const short8*)(Ab + offA1 + mf * 2048);
#pragma unroll
        for (int nf = 0; nf < 4; ++nf) b1[nf] = *(const short8*)(Bb + offB1 + nf * 2048);
        if (t + 1 < NT) STAGE8(aSrc, AbN, 1, (t + 1) << 6);
        __builtin_amdgcn_s_barrier();
        WAIT_LGKM0_FENCED();
        __builtin_amdgcn_s_setprio(1);
#pragma unroll
        for (int mf = 0; mf < 4; ++mf)
#pragma unroll
            for (int nf = 0; nf < 4; ++nf)
                acc[mf][nf] = __builtin_amdgcn_mfma_f32_16x16x32_bf16(
                    a1[mf], b1[nf], acc[mf][nf], 0, 0, 0);
        __builtin_amdgcn_s_setprio(0);
        __builtin_amdgcn_s_barrier();

        // ---- phase 2: A[m4-7]k0; prefetch B(t+2)h0 into CUR buf's B
#pragma unroll
        for (int mf = 0; mf < 4; ++mf) a0[mf] = *(const short8*)(Ab + offA0 + (mf + 4) * 2048);
        if (t + 2 < NT) STAGE8(bSrc, BbC, 0, (t + 2) << 6);
        __builtin_amdgcn_s_barrier();
        WAIT_LGKM0_FENCED();
        __builtin_amdgcn_s_setprio(1);
#pragma unroll
        for (int mf = 0; mf < 4; ++mf)
#pragma unroll
            for (int nf = 0; nf < 4; ++nf)
                acc[mf + 4][nf] = __builtin_amdgcn_mfma_f32_16x16x32_bf16(
                    a0[mf], b0[nf], acc[mf + 4][nf], 0, 0, 0);
        __builtin_amdgcn_s_setprio(0);
        __builtin_amdgcn_s_barrier();

        // ---- phase 3: A[m4-7]k1; prefetch B(t+2)h1; counted vmcnt
#pragma unroll
        for (int mf = 0; mf < 4; ++mf) a1[mf] = *(const short8*)(Ab + offA1 + (mf + 4) * 2048);
        if (t + 2 < NT) {
            STAGE8(bSrc, BbC, 1, (t + 2) << 6);
            asm volatile("s_waitcnt vmcnt(4)" ::: "memory");   // t+1 landed
        } else if (t + 1 < NT) {
            asm volatile("s_waitcnt vmcnt(0)" ::: "memory");   // tail drain
        }
        __builtin_amdgcn_s_barrier();
        WAIT_LGKM0_FENCED();
        __builtin_amdgcn_s_setprio(1);
#pragma unroll
        for (int mf = 0; mf < 4; ++mf)
#pragma unroll
            for (int nf = 0; nf < 4; ++nf)
                acc[mf + 4][nf] = __builtin_amdgcn_mfma_f32_16x16x32_bf16(
                    a1[mf], b1[nf], acc[mf + 4][nf], 0, 0, 0);
        __builtin_amdgcn_s_setprio(0);
        __builtin_amdgcn_s_barrier();
    }

    // Epilogue. C/D map: col = lane&15, row = (lane>>4)*4 + reg
    const int cr = q4 * 4;
    const int cc = l15;

    if (MODE == 1 && n0 >= 2048) {
        const int bb = m0 / SS;
#pragma unroll
        for (int mf = 0; mf < 8; ++mf) {
            int grow = m0 + (wr << 7) + mf * 16 + cr;
            int ssr = grow & (SS - 1);
#pragma unroll
            for (int nf = 0; nf < 4; ++nf) {
                int gcol = n0 + (wc << 6) + nf * 16 + cc;
                float bv = bias[gcol];
                int col = gcol - 2048;
                int hh = col >> 6, dd = col & 63;
                short4v pk;
#pragma unroll
                for (int r = 0; r < 4; ++r) pk[r] = bf16bits(acc[mf][nf][r] + bv);
                *(short4v*)(vT + (size_t)((bb * HH + hh) * 64 + dd) * SS + ssr) = pk;
            }
        }
    } else {
        const float qs = (MODE == 1 && n0 < 1024) ? 0.125f : 1.0f;
#pragma unroll
        for (int mf = 0; mf < 8; ++mf) {
            int grow = m0 + (wr << 7) + mf * 16 + cr;
#pragma unroll
            for (int nf = 0; nf < 4; ++nf) {
                int gcol = n0 + (wc << 6) + nf * 16 + cc;
                float bv = bias[gcol];
#pragma unroll
                for (int r = 0; r < 4; ++r) {
                    float v = (acc[mf][nf][r] + bv) * qs;
                    if constexpr (MODE == 1)
                        ((__hip_bfloat16*)Cv)[(size_t)(grow + r) * N + gcol] =
                            __float2bfloat16(v);
                    else
                        ((float*)Cv)[(size_t)(grow + r) * N + gcol] = v;
                }
            }
        }
    }
}

// ---------------------------------------------------------------------------
// MFMA causal flash attention (round-4 verified). Grid 128 bh x 8 q-blocks
// = 1024 blocks, 4/CU; round-robin dispatch balances the causal triangle
// (round-6 lesson: light+heavy pairing halves TLP, loses ~9us).
// ---------------------------------------------------------------------------
#define PSTR 72

__global__ __launch_bounds__(256) void attn_mfma_kernel(
    const __hip_bfloat16* __restrict__ qkv,
    const __hip_bfloat16* __restrict__ vT,
    __hip_bfloat16* __restrict__ aout)
{
    const int bh = blockIdx.x;
    const int b = bh / HH, h = bh % HH;
    const int q0 = ((int)gridDim.y - 1 - (int)blockIdx.y) * 128;  // heavy first

    __shared__ __hip_bfloat16 Ks[64 * PSTR];     // [key][d]
    __shared__ __hip_bfloat16 Vs[64 * PSTR];     // V^T: [d][key]
    __shared__ __hip_bfloat16 Ps[4][32 * PSTR];  // per-wave P, [q_local][key]

    const int tid  = threadIdx.x;
    const int wave = tid >> 6;
    const int lane = tid & 63;
    const int quad = lane >> 4;
    const int l16  = lane & 15;

    short8 qf[2][2];
#pragma unroll
    for (int t = 0; t < 2; ++t) {
        const __hip_bfloat16* qp = qkv +
            (size_t)(b * SS + q0 + wave * 32 + t * 16 + l16) * 3072 + h * 64 + quad * 8;
        qf[t][0] = *(const short8*)qp;
        qf[t][1] = *(const short8*)(qp + 32);
    }

    float4v o_acc[2][4];
    float l_acc[2][4];
#pragma unroll
    for (int t = 0; t < 2; ++t)
#pragma unroll
        for (int nt = 0; nt < 4; ++nt) o_acc[t][nt] = (float4v){0.f, 0.f, 0.f, 0.f};
#pragma unroll
    for (int t = 0; t < 2; ++t)
#pragma unroll
        for (int r = 0; r < 4; ++r) l_acc[t][r] = 0.f;

    const int sk  = tid & 63;
    const int sdo = (tid >> 6) * 16;
    const int vd  = tid >> 2;
    const int vko = (tid & 3) * 16;
    const int qmin_w = q0 + wave * 32;
    const int nkt = q0 / 64 + 2;

    for (int kt = 0; kt < nkt; ++kt) {
        const int k0 = kt * 64;
        __syncthreads();
        {
            const __hip_bfloat16* kr =
                qkv + (size_t)(b * SS + k0 + sk) * 3072 + 1024 + h * 64 + sdo;
            *(short8*)&Ks[sk * PSTR + sdo]     = *(const short8*)kr;
            *(short8*)&Ks[sk * PSTR + sdo + 8] = *(const short8*)(kr + 8);
            const __hip_bfloat16* vr = vT + (size_t)(bh * 64 + vd) * SS + k0 + vko;
            *(short8*)&Vs[vd * PSTR + vko]     = *(const short8*)vr;
            *(short8*)&Vs[vd * PSTR + vko + 8] = *(const short8*)(vr + 8);
        }
        __syncthreads();
        if (k0 > qmin_w + 31) continue;

        const short* ks = (const short*)Ks;
        float4v sacc[2][4];
#pragma unroll
        for (int t = 0; t < 2; ++t)
#pragma unroll
            for (int nt = 0; nt < 4; ++nt) sacc[t][nt] = (float4v){0.f, 0.f, 0.f, 0.f};
#pragma unroll
        for (int kc = 0; kc < 2; ++kc)
#pragma unroll
            for (int nt = 0; nt < 4; ++nt) {
                short8 kb = *(const short8*)(ks + (nt * 16 + l16) * PSTR + kc * 32 + quad * 8);
                sacc[0][nt] = __builtin_amdgcn_mfma_f32_16x16x32_bf16(qf[0][kc], kb, sacc[0][nt], 0, 0, 0);
                sacc[1][nt] = __builtin_amdgcn_mfma_f32_16x16x32_bf16(qf[1][kc], kb, sacc[1][nt], 0, 0, 0);
            }

        const bool needmask = (k0 + 63 > qmin_w);
        __hip_bfloat16* pw = Ps[wave];
#pragma unroll
        for (int t = 0; t < 2; ++t)
#pragma unroll
            for (int nt = 0; nt < 4; ++nt) {
                int kk = k0 + nt * 16 + l16;
#pragma unroll
                for (int r = 0; r < 4; ++r) {
                    float s = sacc[t][nt][r];
                    if (needmask) {
                        int qq = qmin_w + t * 16 + quad * 4 + r;
                        if (kk > qq) s = -1e10f;
                    }
                    float p = __expf(s);
                    l_acc[t][r] += p;
                    pw[(t * 16 + quad * 4 + r) * PSTR + nt * 16 + l16] =
                        __float2bfloat16(p);
                }
            }

        const short* ps = (const short*)pw;
        const short* vs = (const short*)Vs;
#pragma unroll
        for (int kc = 0; kc < 2; ++kc) {
            short8 pa0 = *(const short8*)(ps + (0 * 16 + l16) * PSTR + kc * 32 + quad * 8);
            short8 pa1 = *(const short8*)(ps + (1 * 16 + l16) * PSTR + kc * 32 + quad * 8);
#pragma unroll
            for (int nt = 0; nt < 4; ++nt) {
                short8 vb = *(const short8*)(vs + (nt * 16 + l16) * PSTR + kc * 32 + quad * 8);
                o_acc[0][nt] = __builtin_amdgcn_mfma_f32_16x16x32_bf16(pa0, vb, o_acc[0][nt], 0, 0, 0);
                o_acc[1][nt] = __builtin_amdgcn_mfma_f32_16x16x32_bf16(pa1, vb, o_acc[1][nt], 0, 0, 0);
            }
        }
    }

#pragma unroll
    for (int t = 0; t < 2; ++t)
#pragma unroll
        for (int r = 0; r < 4; ++r) {
            float l = l_acc[t][r];
            l += __shfl_xor(l, 1);
            l += __shfl_xor(l, 2);
            l += __shfl_xor(l, 4);
            l += __shfl_xor(l, 8);
            float inv = 1.f / l;
            int row = q0 + wave * 32 + t * 16 + quad * 4 + r;
            __hip_bfloat16* op = aout + (size_t)(b * SS + row) * NXX + h * 64 + l16;
#pragma unroll
            for (int nt = 0; nt < 4; ++nt)
                op[nt * 16] = __float2bfloat16(o_acc[t][nt][r] * inv);
        }
}

// ---------------------------------------------------------------------------
// Workspace (88 MB): qkv[0,48M) | vT[48,64M) | xb/amid[64,80M) |
// wT_attn[80,86M) | wT_proj[86,88M)
// ---------------------------------------------------------------------------
extern "C" void kernel_launch(void* const* d_in, const int* in_sizes, int n_in,
                              void* d_out, int out_size, void* d_ws, size_t ws_size,
                              hipStream_t stream)
{
    const float* x      = (const float*)d_in[0];
    const float* w_attn = (const float*)d_in[1];
    const float* b_attn = (const float*)d_in[2];
    const float* w_proj = (const float*)d_in[3];
    const float* b_proj = (const float*)d_in[4];
    float* out = (float*)d_out;

    char* ws = (char*)d_ws;
    __hip_bfloat16* qkv     = (__hip_bfloat16*)ws;
    __hip_bfloat16* vT      = (__hip_bfloat16*)(ws + (size_t)48 * 1024 * 1024);
    __hip_bfloat16* xb      = (__hip_bfloat16*)(ws + (size_t)64 * 1024 * 1024);
    __hip_bfloat16* amid    = xb;
    __hip_bfloat16* wT_attn = (__hip_bfloat16*)(ws + (size_t)80 * 1024 * 1024);
    __hip_bfloat16* wT_proj = (__hip_bfloat16*)(ws + (size_t)86 * 1024 * 1024);

    // One-time opt-in for 128 KiB dynamic LDS on gemm8k<1>; fall back to the
    // verified 64K kernel if the runtime refuses (no wasted launch).
    static int dyn_state = 0;  // 0=unknown, 1=ok, -1=unavailable
    if (dyn_state == 0) {
        hipError_t e = hipFuncSetAttribute(
            reinterpret_cast<const void*>(&gemm8k<1>),
            hipFuncAttributeMaxDynamicSharedMemorySize, 131072);
        dyn_state = (e == hipSuccess) ? 1 : -1;
        (void)hipGetLastError();  // clear any sticky error from the probe
    }

    prep_kernel<<<dim3(12288), dim3(256), 0, stream>>>(
        x, xb, w_attn, wT_attn, w_proj, wT_proj);

    if (dyn_state == 1) {
        // QKV: 32 x 12 = 384 blocks, 256^2 tiles, 128 KiB dynamic LDS
        gemm8k<1><<<dim3((MM / 256) * ((3 * NXX) / 256)), dim3(512), 131072, stream>>>(
            xb, wT_attn, b_attn, qkv, vT, MM, NXX, 3 * NXX);
    } else {
        // fallback: round-4 verified 256x128 (66.7 us)
        gemm256<1, 256, 128><<<dim3((MM / 256) * ((3 * NXX) / 128)), dim3(512), 0, stream>>>(
            xb, wT_attn, b_attn, qkv, vT, MM, NXX, 3 * NXX);
    }

    attn_mfma_kernel<<<dim3(BB * HH, SS / 128), dim3(256), 0, stream>>>(qkv, vT, amid);

    // proj: round-4 verified config (256x128, 256 blocks)
    gemm256<0, 256, 128><<<dim3((MM / 256) * (NXX / 128)), dim3(512), 0, stream>>>(
        amid, wT_proj, b_proj, out, nullptr, MM, NXX, NXX);
}

// Round 9
// 216.228 us; speedup vs baseline: 1.0620x; 1.0620x over previous
//
#include <hip/hip_runtime.h>
#include <hip/hip_bf16.h>

// Problem constants (GPT-2 style attention block)
#define BB 8
#define SS 1024
#define NXX 1024
#define HH 16
#define DD 64
#define MM (BB * SS)

typedef __attribute__((ext_vector_type(8))) short short8;   // 8 bf16 = 4 VGPRs
typedef __attribute__((ext_vector_type(4))) short short4v;  // 4 bf16 = 8 B
typedef __attribute__((ext_vector_type(4))) float float4v;  // MFMA C/D

static __device__ inline short bf16bits(float v) {
    __hip_bfloat16 t = __float2bfloat16(v);
    return *reinterpret_cast<short*>(&t);
}

// ---------------------------------------------------------------------------
// Prep kernel: one launch does x->bf16 convert + both weight transposes.
// ---------------------------------------------------------------------------
__global__ __launch_bounds__(256) void prep_kernel(
    const float* __restrict__ x, __hip_bfloat16* __restrict__ xb,
    const float* __restrict__ w_attn, __hip_bfloat16* __restrict__ wT_attn,
    const float* __restrict__ w_proj, __hip_bfloat16* __restrict__ wT_proj)
{
    __shared__ __hip_bfloat16 tile[32][33];
    const int blk = blockIdx.x;
    const int tid = threadIdx.x;

    if (blk < 8192) {
        int i = blk * 1024 + tid * 4;
        float4 v = *(const float4*)(x + i);
        xb[i + 0] = __float2bfloat16(v.x);
        xb[i + 1] = __float2bfloat16(v.y);
        xb[i + 2] = __float2bfloat16(v.z);
        xb[i + 3] = __float2bfloat16(v.w);
        return;
    }
    const float* W;
    __hip_bfloat16* Wt;
    int K, N, idx;
    if (blk < 8192 + 3072) { idx = blk - 8192;  W = w_attn; Wt = wT_attn; K = NXX; N = 3 * NXX; }
    else                   { idx = blk - 11264; W = w_proj; Wt = wT_proj; K = NXX; N = NXX; }
    const int k0 = (idx % (K / 32)) * 32;
    const int n0 = (idx / (K / 32)) * 32;
    const int tx = tid % 32;
    const int ty = tid / 32;
#pragma unroll
    for (int p = 0; p < 4; ++p) {
        int k = ty + p * 8;
        tile[k][tx] = __float2bfloat16(W[(size_t)(k0 + k) * N + n0 + tx]);
    }
    __syncthreads();
#pragma unroll
    for (int p = 0; p < 4; ++p) {
        int nn = ty + p * 8;
        Wt[(size_t)(n0 + nn) * K + k0 + tx] = tile[tx][nn];
    }
}

#define WAIT_LGKM0_FENCED()                                                    \
    asm volatile("s_waitcnt lgkmcnt(0)" ::: "memory");                         \
    __builtin_amdgcn_sched_barrier(0);

#define STAGE_A(DST, kk)                                                       \
    {                                                                          \
        _Pragma("unroll") for (int j_ = 0; j_ < LA; ++j_) {                    \
            const __hip_bfloat16* s_ = aSrc + (size_t)(j_ * 128) * K + (kk);   \
            char* d_ = (char*)(DST) + j_ * 8192 + (wave << 10);                \
            __builtin_amdgcn_global_load_lds(                                  \
                (const __attribute__((address_space(1))) void*)s_,             \
                (__attribute__((address_space(3))) void*)d_, 16, 0, 0);        \
        }                                                                      \
    }

#define STAGE_B(DST, kk)                                                       \
    {                                                                          \
        _Pragma("unroll") for (int j_ = 0; j_ < LB; ++j_) {                    \
            const __hip_bfloat16* s_ = bSrc + (size_t)(j_ * 128) * K + (kk);   \
            char* d_ = (char*)(DST) + j_ * 8192 + (wave << 10);                \
            __builtin_amdgcn_global_load_lds(                                  \
                (const __attribute__((address_space(1))) void*)s_,             \
                (__attribute__((address_space(3))) void*)d_, 16, 0, 0);        \
        }                                                                      \
    }

// ---------------------------------------------------------------------------
// gemm3b: BMxBN 8-wave GEMM, ONE phase per K-tile, BOTH operands
// TRIPLE-buffered in 72 KiB DYNAMIC LDS (2 blocks/CU: 2x72K=144K <= 160K).
//   Rationale (r4-r8 gradient): round-4's 2-phase structure paid 4 barriers
//   + 2 lgkm drains per K-tile only because 64 KiB static forced phase-
//   ordered region reuse for depth-2 staging. Triple-buffering both operands
//   gives depth-2 cleanly: tile t stages t+2 into the buffer tile t-1
//   vacated at the previous closing barrier. 2 barriers + 1 lgkm per K-tile
//   for the same 16 MFMA/wave; co-residency (the proven lever) unchanged.
//
// Per K-tile t (idx ia = t%3):
//   ds a[0..3] from A[ia], b[0..NF-1] from B[ia] (4+NF x b128)
//   STAGE_A(t+2)->A[(t+2)%3]; STAGE_B(t+2)->B[(t+2)%3]   (regions free)
//   vmcnt(3)   [outstanding: tile t+1 (3) + tile t+2 (3); retires t+1,
//               which was issued ONE FULL K-TILE earlier -> latency covered]
//   bar; lgkm0+fence (rule #18); prio1; 16 MFMA; prio0; bar
// Tail: t=NT-2 -> vmcnt(0). Prologue: tiles 0,1 staged; vmcnt(3); bar.
// Swizzle (verified 0 conflicts): 16B slots of 64B rows, slot ^= (row>>1)&3,
// inverse pre-applied on global source (rule #21).
// MODE 0: fp32 C (proj). MODE 1: QKV -- bf16 Q (x0.125)/K; V transposed to
// vT[b,h,d,s]. Grid: grouped-M (GM=8, N-fastest) under XCD bijective swizzle.
// ---------------------------------------------------------------------------
template <int MODE, int BM, int BN>
__global__ __launch_bounds__(512, 2) void gemm3b(
    const __hip_bfloat16* __restrict__ A,   // M x K row-major
    const __hip_bfloat16* __restrict__ Bt,  // N x K row-major
    const float* __restrict__ bias,
    void* __restrict__ Cv,                  // M x N
    __hip_bfloat16* __restrict__ vT,        // MODE 1 only
    int M, int K, int N)
{
    constexpr int NWM = BM / 64;
    constexpr int NWN = 8 / NWM;
    constexpr int WCOLS = BN / NWN;
    constexpr int NF = WCOLS / 16;
    constexpr int ASZ = BM * 64;
    constexpr int BSZ = BN * 64;
    constexpr int LA = BM / 128;
    constexpr int LB = BN / 128;

    extern __shared__ __attribute__((aligned(16))) char smem[];

    const int tid  = threadIdx.x;
    const int wave = tid >> 6;
    const int lane = tid & 63;
    const int wm = (wave / NWN) * 64;
    const int wn = (wave % NWN) * WCOLS;

    const int nwg = (int)gridDim.x;
    const int cpx = nwg >> 3;
    const int bid = (int)blockIdx.x;
    const int swz = (bid & 7) * cpx + (bid >> 3);
    const int ntN = N / BN;
    const int width = ntN << 3;
    const int group = swz / width;
    const int w = swz % width;
    const int m0 = (group * 8 + (w & 7)) * BM;
    const int n0 = (w >> 3) * BN;

    const int NT = K >> 5;

    const int row_s  = tid >> 2;
    const int srccol = (((tid & 3) ^ ((tid >> 3) & 3)) << 3);
    const __hip_bfloat16* aSrc = A  + (size_t)(m0 + row_s) * K + srccol;
    const __hip_bfloat16* bSrc = Bt + (size_t)(n0 + row_s) * K + srccol;

    const int l15 = lane & 15, q4 = lane >> 4;
    const int sslot = (q4 ^ ((l15 >> 1) & 3)) << 4;
    const int offA = (wm + l15) * 64 + sslot;
    const int offB = (wn + l15) * 64 + sslot;

    float4v acc[4][NF];
#pragma unroll
    for (int i = 0; i < 4; ++i)
#pragma unroll
        for (int j = 0; j < NF; ++j) acc[i][j] = (float4v){0.f, 0.f, 0.f, 0.f};

    char* const Abuf0 = (char*)smem;            // A[0..2] @ i*ASZ
    char* const Bbuf0 = (char*)smem + 3 * ASZ;  // B[0..2] @ i*BSZ

    // prologue: tiles 0 and 1 for both operands; keep tile 1 (3 loads) in flight
    STAGE_A(Abuf0,       0);
    STAGE_B(Bbuf0,       0);
    STAGE_A(Abuf0 + ASZ, 32);
    STAGE_B(Bbuf0 + BSZ, 32);
    asm volatile("s_waitcnt vmcnt(3)" ::: "memory");
    __builtin_amdgcn_s_barrier();

    int ia = 0;  // t % 3
    for (int t = 0; t < NT; ++t) {
        const char* Ab = Abuf0 + ia * ASZ;
        const char* Bb = Bbuf0 + ia * BSZ;
        const int ia2 = (ia >= 1) ? ia - 1 : 2;   // (t+2) % 3

        short8 a[4], b[NF];
#pragma unroll
        for (int mf = 0; mf < 4; ++mf) a[mf] = *(const short8*)(Ab + offA + mf * 1024);
#pragma unroll
        for (int nf = 0; nf < NF; ++nf) b[nf] = *(const short8*)(Bb + offB + nf * 1024);

        if (t + 2 < NT) {
            STAGE_A(Abuf0 + ia2 * ASZ, (t + 2) << 5);
            STAGE_B(Bbuf0 + ia2 * BSZ, (t + 2) << 5);
            asm volatile("s_waitcnt vmcnt(3)" ::: "memory");  // tile t+1 ready
        } else if (t + 1 < NT) {
            asm volatile("s_waitcnt vmcnt(0)" ::: "memory");  // tail drain
        }
        __builtin_amdgcn_s_barrier();
        WAIT_LGKM0_FENCED();
        __builtin_amdgcn_s_setprio(1);
#pragma unroll
        for (int mf = 0; mf < 4; ++mf)
#pragma unroll
            for (int nf = 0; nf < NF; ++nf)
                acc[mf][nf] = __builtin_amdgcn_mfma_f32_16x16x32_bf16(
                    a[mf], b[nf], acc[mf][nf], 0, 0, 0);
        __builtin_amdgcn_s_setprio(0);
        __builtin_amdgcn_s_barrier();

        ia = (ia == 2) ? 0 : ia + 1;
    }

    // Epilogue. C/D map: col = lane&15, row = (lane>>4)*4 + reg
    const int cr = q4 * 4;
    const int cc = l15;

    if (MODE == 1 && n0 >= 2048) {
        const int bb = m0 / SS;
#pragma unroll
        for (int mf = 0; mf < 4; ++mf) {
            int grow = m0 + wm + mf * 16 + cr;
            int ssr = grow & (SS - 1);
#pragma unroll
            for (int nf = 0; nf < NF; ++nf) {
                int gcol = n0 + wn + nf * 16 + cc;
                float bv = bias[gcol];
                int col = gcol - 2048;
                int hh = col >> 6, dd = col & 63;
                short4v pk;
#pragma unroll
                for (int r = 0; r < 4; ++r) pk[r] = bf16bits(acc[mf][nf][r] + bv);
                *(short4v*)(vT + (size_t)((bb * HH + hh) * 64 + dd) * SS + ssr) = pk;
            }
        }
    } else {
        const float qs = (MODE == 1 && n0 < 1024) ? 0.125f : 1.0f;
#pragma unroll
        for (int mf = 0; mf < 4; ++mf) {
            int grow = m0 + wm + mf * 16 + cr;
#pragma unroll
            for (int nf = 0; nf < NF; ++nf) {
                int gcol = n0 + wn + nf * 16 + cc;
                float bv = bias[gcol];
#pragma unroll
                for (int r = 0; r < 4; ++r) {
                    float v = (acc[mf][nf][r] + bv) * qs;
                    if constexpr (MODE == 1)
                        ((__hip_bfloat16*)Cv)[(size_t)(grow + r) * N + gcol] =
                            __float2bfloat16(v);
                    else
                        ((float*)Cv)[(size_t)(grow + r) * N + gcol] = v;
                }
            }
        }
    }
}

// ---------------------------------------------------------------------------
// gemm256: round-4 HW-verified 2-phase kernel (<=64 KiB static LDS), kept as
// fallback when dynamic-LDS opt-in fails. <1,256,128>: 66.7us, MfmaUtil 32%.
// ---------------------------------------------------------------------------
#define WAIT_VMCNT_LT()                                                        \
    if constexpr (LT == 3) { asm volatile("s_waitcnt vmcnt(3)" ::: "memory"); }\
    else                   { asm volatile("s_waitcnt vmcnt(2)" ::: "memory"); }

template <int MODE, int BM, int BN>
__global__ __launch_bounds__(512, 2) void gemm256(
    const __hip_bfloat16* __restrict__ A,   // M x K row-major
    const __hip_bfloat16* __restrict__ Bt,  // N x K row-major
    const float* __restrict__ bias,
    void* __restrict__ Cv,                  // M x N
    __hip_bfloat16* __restrict__ vT,        // MODE 1 only
    int M, int K, int N)
{
    constexpr int NWM = BM / 64;
    constexpr int NWN = 8 / NWM;
    constexpr int WCOLS = BN / NWN;
    constexpr int NF = WCOLS / 16;
    constexpr int ASZ = BM * 64;
    constexpr int BSZ = BN * 64;
    constexpr int LA = BM / 128;
    constexpr int LB = BN / 128;
    constexpr int LT = LA + LB;

    __shared__ __attribute__((aligned(16))) char smem[3 * ASZ + 2 * BSZ];

    const int tid  = threadIdx.x;
    const int wave = tid >> 6;
    const int lane = tid & 63;
    const int wm = (wave / NWN) * 64;
    const int wn = (wave % NWN) * WCOLS;

    const int nwg = (int)gridDim.x;
    const int cpx = nwg >> 3;
    const int bid = (int)blockIdx.x;
    const int swz = (bid & 7) * cpx + (bid >> 3);
    const int ntN = N / BN;
    const int width = ntN << 3;
    const int group = swz / width;
    const int w = swz % width;
    const int m0 = (group * 8 + (w & 7)) * BM;
    const int n0 = (w >> 3) * BN;

    const int NT = K >> 5;

    const int row_s  = tid >> 2;
    const int srccol = (((tid & 3) ^ ((tid >> 3) & 3)) << 3);
    const __hip_bfloat16* aSrc = A  + (size_t)(m0 + row_s) * K + srccol;
    const __hip_bfloat16* bSrc = Bt + (size_t)(n0 + row_s) * K + srccol;

    const int l15 = lane & 15, q4 = lane >> 4;
    const int sslot = (q4 ^ ((l15 >> 1) & 3)) << 4;
    const int offA = (wm + l15) * 64 + sslot;
    const int offB = (wn + l15) * 64 + sslot;

    float4v acc[4][NF];
#pragma unroll
    for (int i = 0; i < 4; ++i)
#pragma unroll
        for (int j = 0; j < NF; ++j) acc[i][j] = (float4v){0.f, 0.f, 0.f, 0.f};

    char* const Abuf0 = (char*)smem;
    char* const Bbuf0 = (char*)smem + 3 * ASZ;

    STAGE_A(Abuf0,       0);
    STAGE_B(Bbuf0,       0);
    STAGE_A(Abuf0 + ASZ, 32);
    STAGE_B(Bbuf0 + BSZ, 32);
    WAIT_VMCNT_LT();
    __builtin_amdgcn_s_barrier();

    int ia = 0;
    for (int t = 0; t < NT; ++t) {
        const char* Ab = Abuf0 + ia * ASZ;
        char* Bb = Bbuf0 + (t & 1) * BSZ;
        const int ia2 = (ia == 0) ? 2 : ia - 1;

        short8 a[4], b[NF];

#pragma unroll
        for (int mf = 0; mf < 2; ++mf) a[mf] = *(const short8*)(Ab + offA + mf * 1024);
#pragma unroll
        for (int nf = 0; nf < NF; ++nf) b[nf] = *(const short8*)(Bb + offB + nf * 1024);
        if (t + 2 < NT) STAGE_A(Abuf0 + ia2 * ASZ, (t + 2) << 5);
        __builtin_amdgcn_s_barrier();
        WAIT_LGKM0_FENCED();
        __builtin_amdgcn_s_setprio(1);
#pragma unroll
        for (int mf = 0; mf < 2; ++mf)
#pragma unroll
            for (int nf = 0; nf < NF; ++nf)
                acc[mf][nf] = __builtin_amdgcn_mfma_f32_16x16x32_bf16(
                    a[mf], b[nf], acc[mf][nf], 0, 0, 0);
        __builtin_amdgcn_s_setprio(0);
        __builtin_amdgcn_s_barrier();

#pragma unroll
        for (int mf = 2; mf < 4; ++mf) a[mf] = *(const short8*)(Ab + offA + mf * 1024);
        if (t + 2 < NT) {
            STAGE_B(Bb, (t + 2) << 5);
            WAIT_VMCNT_LT();
        } else if (t + 1 < NT) {
            asm volatile("s_waitcnt vmcnt(0)" ::: "memory");
        }
        __builtin_amdgcn_s_barrier();
        WAIT_LGKM0_FENCED();
        __builtin_amdgcn_s_setprio(1);
#pragma unroll
        for (int mf = 2; mf < 4; ++mf)
#pragma unroll
            for (int nf = 0; nf < NF; ++nf)
                acc[mf][nf] = __builtin_amdgcn_mfma_f32_16x16x32_bf16(
                    a[mf], b[nf], acc[mf][nf], 0, 0, 0);
        __builtin_amdgcn_s_setprio(0);
        __builtin_amdgcn_s_barrier();

        ia = (ia == 2) ? 0 : ia + 1;
    }

    const int cr = q4 * 4;
    const int cc = l15;

    if (MODE == 1 && n0 >= 2048) {
        const int bb = m0 / SS;
#pragma unroll
        for (int mf = 0; mf < 4; ++mf) {
            int grow = m0 + wm + mf * 16 + cr;
            int ssr = grow & (SS - 1);
#pragma unroll
            for (int nf = 0; nf < NF; ++nf) {
                int gcol = n0 + wn + nf * 16 + cc;
                float bv = bias[gcol];
                int col = gcol - 2048;
                int hh = col >> 6, dd = col & 63;
                short4v pk;
#pragma unroll
                for (int r = 0; r < 4; ++r) pk[r] = bf16bits(acc[mf][nf][r] + bv);
                *(short4v*)(vT + (size_t)((bb * HH + hh) * 64 + dd) * SS + ssr) = pk;
            }
        }
    } else {
        const float qs = (MODE == 1 && n0 < 1024) ? 0.125f : 1.0f;
#pragma unroll
        for (int mf = 0; mf < 4; ++mf) {
            int grow = m0 + wm + mf * 16 + cr;
#pragma unroll
            for (int nf = 0; nf < NF; ++nf) {
                int gcol = n0 + wn + nf * 16 + cc;
                float bv = bias[gcol];
#pragma unroll
                for (int r = 0; r < 4; ++r) {
                    float v = (acc[mf][nf][r] + bv) * qs;
                    if constexpr (MODE == 1)
                        ((__hip_bfloat16*)Cv)[(size_t)(grow + r) * N + gcol] =
                            __float2bfloat16(v);
                    else
                        ((float*)Cv)[(size_t)(grow + r) * N + gcol] = v;
                }
            }
        }
    }
}

// ---------------------------------------------------------------------------
// MFMA causal flash attention (round-4 verified). Grid 128 bh x 8 q-blocks
// = 1024 blocks, 4/CU; round-robin dispatch balances the causal triangle
// (round-6 lesson: light+heavy pairing halves TLP, loses ~9us).
// ---------------------------------------------------------------------------
#define PSTR 72

__global__ __launch_bounds__(256) void attn_mfma_kernel(
    const __hip_bfloat16* __restrict__ qkv,
    const __hip_bfloat16* __restrict__ vT,
    __hip_bfloat16* __restrict__ aout)
{
    const int bh = blockIdx.x;
    const int b = bh / HH, h = bh % HH;
    const int q0 = ((int)gridDim.y - 1 - (int)blockIdx.y) * 128;  // heavy first

    __shared__ __hip_bfloat16 Ks[64 * PSTR];     // [key][d]
    __shared__ __hip_bfloat16 Vs[64 * PSTR];     // V^T: [d][key]
    __shared__ __hip_bfloat16 Ps[4][32 * PSTR];  // per-wave P, [q_local][key]

    const int tid  = threadIdx.x;
    const int wave = tid >> 6;
    const int lane = tid & 63;
    const int quad = lane >> 4;
    const int l16  = lane & 15;

    short8 qf[2][2];
#pragma unroll
    for (int t = 0; t < 2; ++t) {
        const __hip_bfloat16* qp = qkv +
            (size_t)(b * SS + q0 + wave * 32 + t * 16 + l16) * 3072 + h * 64 + quad * 8;
        qf[t][0] = *(const short8*)qp;
        qf[t][1] = *(const short8*)(qp + 32);
    }

    float4v o_acc[2][4];
    float l_acc[2][4];
#pragma unroll
    for (int t = 0; t < 2; ++t)
#pragma unroll
        for (int nt = 0; nt < 4; ++nt) o_acc[t][nt] = (float4v){0.f, 0.f, 0.f, 0.f};
#pragma unroll
    for (int t = 0; t < 2; ++t)
#pragma unroll
        for (int r = 0; r < 4; ++r) l_acc[t][r] = 0.f;

    const int sk  = tid & 63;
    const int sdo = (tid >> 6) * 16;
    const int vd  = tid >> 2;
    const int vko = (tid & 3) * 16;
    const int qmin_w = q0 + wave * 32;
    const int nkt = q0 / 64 + 2;

    for (int kt = 0; kt < nkt; ++kt) {
        const int k0 = kt * 64;
        __syncthreads();
        {
            const __hip_bfloat16* kr =
                qkv + (size_t)(b * SS + k0 + sk) * 3072 + 1024 + h * 64 + sdo;
            *(short8*)&Ks[sk * PSTR + sdo]     = *(const short8*)kr;
            *(short8*)&Ks[sk * PSTR + sdo + 8] = *(const short8*)(kr + 8);
            const __hip_bfloat16* vr = vT + (size_t)(bh * 64 + vd) * SS + k0 + vko;
            *(short8*)&Vs[vd * PSTR + vko]     = *(const short8*)vr;
            *(short8*)&Vs[vd * PSTR + vko + 8] = *(const short8*)(vr + 8);
        }
        __syncthreads();
        if (k0 > qmin_w + 31) continue;

        const short* ks = (const short*)Ks;
        float4v sacc[2][4];
#pragma unroll
        for (int t = 0; t < 2; ++t)
#pragma unroll
            for (int nt = 0; nt < 4; ++nt) sacc[t][nt] = (float4v){0.f, 0.f, 0.f, 0.f};
#pragma unroll
        for (int kc = 0; kc < 2; ++kc)
#pragma unroll
            for (int nt = 0; nt < 4; ++nt) {
                short8 kb = *(const short8*)(ks + (nt * 16 + l16) * PSTR + kc * 32 + quad * 8);
                sacc[0][nt] = __builtin_amdgcn_mfma_f32_16x16x32_bf16(qf[0][kc], kb, sacc[0][nt], 0, 0, 0);
                sacc[1][nt] = __builtin_amdgcn_mfma_f32_16x16x32_bf16(qf[1][kc], kb, sacc[1][nt], 0, 0, 0);
            }

        const bool needmask = (k0 + 63 > qmin_w);
        __hip_bfloat16* pw = Ps[wave];
#pragma unroll
        for (int t = 0; t < 2; ++t)
#pragma unroll
            for (int nt = 0; nt < 4; ++nt) {
                int kk = k0 + nt * 16 + l16;
#pragma unroll
                for (int r = 0; r < 4; ++r) {
                    float s = sacc[t][nt][r];
                    if (needmask) {
                        int qq = qmin_w + t * 16 + quad * 4 + r;
                        if (kk > qq) s = -1e10f;
                    }
                    float p = __expf(s);
                    l_acc[t][r] += p;
                    pw[(t * 16 + quad * 4 + r) * PSTR + nt * 16 + l16] =
                        __float2bfloat16(p);
                }
            }

        const short* ps = (const short*)pw;
        const short* vs = (const short*)Vs;
#pragma unroll
        for (int kc = 0; kc < 2; ++kc) {
            short8 pa0 = *(const short8*)(ps + (0 * 16 + l16) * PSTR + kc * 32 + quad * 8);
            short8 pa1 = *(const short8*)(ps + (1 * 16 + l16) * PSTR + kc * 32 + quad * 8);
#pragma unroll
            for (int nt = 0; nt < 4; ++nt) {
                short8 vb = *(const short8*)(vs + (nt * 16 + l16) * PSTR + kc * 32 + quad * 8);
                o_acc[0][nt] = __builtin_amdgcn_mfma_f32_16x16x32_bf16(pa0, vb, o_acc[0][nt], 0, 0, 0);
                o_acc[1][nt] = __builtin_amdgcn_mfma_f32_16x16x32_bf16(pa1, vb, o_acc[1][nt], 0, 0, 0);
            }
        }
    }

#pragma unroll
    for (int t = 0; t < 2; ++t)
#pragma unroll
        for (int r = 0; r < 4; ++r) {
            float l = l_acc[t][r];
            l += __shfl_xor(l, 1);
            l += __shfl_xor(l, 2);
            l += __shfl_xor(l, 4);
            l += __shfl_xor(l, 8);
            float inv = 1.f / l;
            int row = q0 + wave * 32 + t * 16 + quad * 4 + r;
            __hip_bfloat16* op = aout + (size_t)(b * SS + row) * NXX + h * 64 + l16;
#pragma unroll
            for (int nt = 0; nt < 4; ++nt)
                op[nt * 16] = __float2bfloat16(o_acc[t][nt][r] * inv);
        }
}

// ---------------------------------------------------------------------------
// Workspace (88 MB): qkv[0,48M) | vT[48,64M) | xb/amid[64,80M) |
// wT_attn[80,86M) | wT_proj[86,88M)
// ---------------------------------------------------------------------------
extern "C" void kernel_launch(void* const* d_in, const int* in_sizes, int n_in,
                              void* d_out, int out_size, void* d_ws, size_t ws_size,
                              hipStream_t stream)
{
    const float* x      = (const float*)d_in[0];
    const float* w_attn = (const float*)d_in[1];
    const float* b_attn = (const float*)d_in[2];
    const float* w_proj = (const float*)d_in[3];
    const float* b_proj = (const float*)d_in[4];
    float* out = (float*)d_out;

    char* ws = (char*)d_ws;
    __hip_bfloat16* qkv     = (__hip_bfloat16*)ws;
    __hip_bfloat16* vT      = (__hip_bfloat16*)(ws + (size_t)48 * 1024 * 1024);
    __hip_bfloat16* xb      = (__hip_bfloat16*)(ws + (size_t)64 * 1024 * 1024);
    __hip_bfloat16* amid    = xb;
    __hip_bfloat16* wT_attn = (__hip_bfloat16*)(ws + (size_t)80 * 1024 * 1024);
    __hip_bfloat16* wT_proj = (__hip_bfloat16*)(ws + (size_t)86 * 1024 * 1024);

    // 72 KiB dynamic LDS (3xA + 3xB buffers): 3*16384 + 3*8192 = 73728 B.
    constexpr int DYN_LDS = 3 * (256 * 64) + 3 * (128 * 64);
    static int dyn_state = 0;  // 0=unknown, 1=ok, -1=unavailable
    if (dyn_state == 0) {
        hipError_t e1 = hipFuncSetAttribute(
            reinterpret_cast<const void*>(&gemm3b<1, 256, 128>),
            hipFuncAttributeMaxDynamicSharedMemorySize, DYN_LDS);
        hipError_t e2 = hipFuncSetAttribute(
            reinterpret_cast<const void*>(&gemm3b<0, 256, 128>),
            hipFuncAttributeMaxDynamicSharedMemorySize, DYN_LDS);
        dyn_state = (e1 == hipSuccess && e2 == hipSuccess) ? 1 : -1;
        (void)hipGetLastError();  // clear any sticky error from the probe
    }

    prep_kernel<<<dim3(12288), dim3(256), 0, stream>>>(
        x, xb, w_attn, wT_attn, w_proj, wT_proj);

    if (dyn_state == 1) {
        // QKV: 32 x 24 = 768 blocks, single-phase triple-buffered, 2 blk/CU
        gemm3b<1, 256, 128><<<dim3((MM / 256) * ((3 * NXX) / 128)), dim3(512),
                              DYN_LDS, stream>>>(
            xb, wT_attn, b_attn, qkv, vT, MM, NXX, 3 * NXX);
    } else {
        gemm256<1, 256, 128><<<dim3((MM / 256) * ((3 * NXX) / 128)), dim3(512), 0, stream>>>(
            xb, wT_attn, b_attn, qkv, vT, MM, NXX, 3 * NXX);
    }

    attn_mfma_kernel<<<dim3(BB * HH, SS / 128), dim3(256), 0, stream>>>(qkv, vT, amid);

    if (dyn_state == 1) {
        // proj: 32 x 8 = 256 blocks
        gemm3b<0, 256, 128><<<dim3((MM / 256) * (NXX / 128)), dim3(512),
                              DYN_LDS, stream>>>(
            amid, wT_proj, b_proj, out, nullptr, MM, NXX, NXX);
    } else {
        gemm256<0, 256, 128><<<dim3((MM / 256) * (NXX / 128)), dim3(512), 0, stream>>>(
            amid, wT_proj, b_proj, out, nullptr, MM, NXX, NXX);
    }
}